// Round 1
// baseline (1121.490 us; speedup 1.0000x reference)
//
#include <hip/hip_runtime.h>

// alpha-entmax (Peters et al.) via bisection, one 64-lane wave per row of 1024.
// Row held entirely in registers (16 f32/lane); reductions via __shfl_xor.

__device__ __forceinline__ float wave_sum(float v) {
#pragma unroll
  for (int off = 32; off > 0; off >>= 1) v += __shfl_xor(v, off, 64);
  return v;
}

__device__ __forceinline__ float wave_max(float v) {
#pragma unroll
  for (int off = 32; off > 0; off >>= 1) v = fmaxf(v, __shfl_xor(v, off, 64));
  return v;
}

// clip(diff, 0)^inv  with 0^inv == 0 (guarded select; log2(0) = -inf path avoided)
__device__ __forceinline__ float pow_clip(float diff, float inv) {
  float u = fmaxf(diff, 0.0f);
  float r = exp2f(inv * __log2f(u));
  return u > 0.0f ? r : 0.0f;
}

#define NITER 50

__global__ __launch_bounds__(256) void entmax_kernel(
    const float* __restrict__ X, const float* __restrict__ A,
    float* __restrict__ O, int nrows) {
  const int lane = threadIdx.x & 63;
  const int wid  = threadIdx.x >> 6;
  const long long row = (long long)blockIdx.x * 4 + wid;
  if (row >= nrows) return;

  const float* xr = X + row * 1024;
  float* orow     = O + row * 1024;

  // rows are [B,H,Q] flattened; Q=1024 -> head = (row>>10) & 15
  const int h = (int)((row >> 10) & 15);
  const float a   = 1.01f + 0.98f * A[h];
  const float am1 = a - 1.0f;
  const float inv = 1.0f / am1;

  // load row, scale by (alpha-1). Element j of lane l = x[c*256 + l*4 + k].
  float xs[16];
#pragma unroll
  for (int c = 0; c < 4; ++c) {
    float4 t = reinterpret_cast<const float4*>(xr)[c * 64 + lane];
    xs[4 * c + 0] = t.x * am1;
    xs[4 * c + 1] = t.y * am1;
    xs[4 * c + 2] = t.z * am1;
    xs[4 * c + 3] = t.w * am1;
  }

  float m = xs[0];
#pragma unroll
  for (int j = 1; j < 16; ++j) m = fmaxf(m, xs[j]);
  m = wave_max(m);

  float tau_lo = m - 1.0f;                      // m - gp(1)
  float tau_hi = m - exp2f(-10.0f * inv);       // m - (1/1024)^inv

  float s0 = 0.0f;
#pragma unroll
  for (int j = 0; j < 16; ++j) s0 += pow_clip(xs[j] - tau_lo, inv);
  const float f_lo = wave_sum(s0) - 1.0f;

  float dm    = tau_hi - tau_lo;
  float tau_m = tau_lo;
  for (int it = 0; it < NITER; ++it) {
    dm *= 0.5f;
    tau_m = tau_lo + dm;
    float sm = 0.0f;
#pragma unroll
    for (int j = 0; j < 16; ++j) sm += pow_clip(xs[j] - tau_m, inv);
    const float f_m = wave_sum(sm) - 1.0f;     // wave-uniform after butterfly
    if (f_m * f_lo >= 0.0f) tau_lo = tau_m;
  }

  // final p at last midpoint tau_m, then normalize (ensure_sum_one)
  float p[16];
  float tot = 0.0f;
#pragma unroll
  for (int j = 0; j < 16; ++j) {
    p[j] = pow_clip(xs[j] - tau_m, inv);
    tot += p[j];
  }
  tot = wave_sum(tot);
  const float r = 1.0f / tot;

#pragma unroll
  for (int c = 0; c < 4; ++c) {
    float4 t;
    t.x = p[4 * c + 0] * r;
    t.y = p[4 * c + 1] * r;
    t.z = p[4 * c + 2] * r;
    t.w = p[4 * c + 3] * r;
    reinterpret_cast<float4*>(orow)[c * 64 + lane] = t;
  }
}

extern "C" void kernel_launch(void* const* d_in, const int* in_sizes, int n_in,
                              void* d_out, int out_size, void* d_ws, size_t ws_size,
                              hipStream_t stream) {
  const float* X = (const float*)d_in[0];
  const float* A = (const float*)d_in[1];
  float* O       = (float*)d_out;
  const int nrows = in_sizes[0] / 1024;                 // 65536
  const int blocks = (nrows + 3) / 4;                   // 4 waves (rows) per 256-thread block
  hipLaunchKernelGGL(entmax_kernel, dim3(blocks), dim3(256), 0, stream,
                     X, A, O, nrows);
}

// Round 2
// 160.608 us; speedup vs baseline: 6.9828x; 6.9828x over previous
//
#include <hip/hip_runtime.h>

// alpha-entmax via Newton's method on f(tau) = sum((xs - tau)_+^inv) - 1.
// f is convex decreasing for inv >= 1 (always true: alpha in (1.01, 1.99]),
// so Newton from tau0 = max-1 (f >= 0 there) converges monotonically without
// overshoot to the same root the reference's 50-step f32 bisection reaches.
// One 64-lane wave per row of 1024; row in registers; shuffle reductions.

__device__ __forceinline__ float wave_sum(float v) {
#pragma unroll
  for (int off = 32; off > 0; off >>= 1) v += __shfl_xor(v, off, 64);
  return v;
}

__device__ __forceinline__ float wave_max(float v) {
#pragma unroll
  for (int off = 32; off > 0; off >>= 1) v = fmaxf(v, __shfl_xor(v, off, 64));
  return v;
}

#define MAXIT 16

__global__ __launch_bounds__(256) void entmax_newton(
    const float* __restrict__ X, const float* __restrict__ A,
    float* __restrict__ O, int nrows) {
  const int lane = threadIdx.x & 63;
  const int wid  = threadIdx.x >> 6;
  const long long row = (long long)blockIdx.x * 4 + wid;
  if (row >= nrows) return;

  const float* xr = X + row * 1024;
  float* orow     = O + row * 1024;

  // rows are [B,H,Q] flattened; Q=1024 -> head = (row>>10) & 15
  const int h = (int)((row >> 10) & 15);
  const float a   = 1.01f + 0.98f * A[h];
  const float am1 = a - 1.0f;
  const float inv = 1.0f / am1;       // in [1.0101, 100]
  const float c1  = inv - 1.0f;       // > 0 always

  // load row, scale by (alpha-1)
  float xs[16];
#pragma unroll
  for (int c = 0; c < 4; ++c) {
    float4 t = reinterpret_cast<const float4*>(xr)[c * 64 + lane];
    xs[4 * c + 0] = t.x * am1;
    xs[4 * c + 1] = t.y * am1;
    xs[4 * c + 2] = t.z * am1;
    xs[4 * c + 3] = t.w * am1;
  }

  float m = xs[0];
#pragma unroll
  for (int j = 1; j < 16; ++j) m = fmaxf(m, xs[j]);
  m = wave_max(m);

  float tau = m - 1.0f;   // f(tau0) >= 0: max element contributes exactly 1

  for (int it = 0; it < MAXIT; ++it) {
    float fs = 0.0f, gs = 0.0f;
#pragma unroll
    for (int j = 0; j < 16; ++j) {
      float u = fmaxf(xs[j] - tau, 0.0f);
      float l = __builtin_amdgcn_logf(u);        // log2; log2(0) = -inf
      float e = __builtin_amdgcn_exp2f(c1 * l);  // u^(inv-1); exp2(-inf) = 0
      fs = fmaf(e, u, fs);                       // u^inv accumulation
      gs += e;
    }
    const float f = wave_sum(fs) - 1.0f;
    const float g = wave_sum(gs);                // wave-uniform
    if (!(g > 0.0f)) break;
    const float step = f / (inv * g);            // f' = -inv*g
    tau += step;
    // wave-uniform early exit: converged to ~f32 precision
    if (!(fabsf(step) > 1e-7f * fmaxf(fabsf(tau), 1.0f))) break;
  }

  // final p at converged tau, then normalize (ensure_sum_one)
  float p[16];
  float tot = 0.0f;
#pragma unroll
  for (int j = 0; j < 16; ++j) {
    float u = fmaxf(xs[j] - tau, 0.0f);
    float l = __builtin_amdgcn_logf(u);
    p[j] = __builtin_amdgcn_exp2f(inv * l);      // u^inv, 0 -> 0 naturally
    tot += p[j];
  }
  tot = wave_sum(tot);
  const float r = 1.0f / tot;

#pragma unroll
  for (int c = 0; c < 4; ++c) {
    float4 t;
    t.x = p[4 * c + 0] * r;
    t.y = p[4 * c + 1] * r;
    t.z = p[4 * c + 2] * r;
    t.w = p[4 * c + 3] * r;
    reinterpret_cast<float4*>(orow)[c * 64 + lane] = t;
  }
}

extern "C" void kernel_launch(void* const* d_in, const int* in_sizes, int n_in,
                              void* d_out, int out_size, void* d_ws, size_t ws_size,
                              hipStream_t stream) {
  const float* X = (const float*)d_in[0];
  const float* A = (const float*)d_in[1];
  float* O       = (float*)d_out;
  const int nrows = in_sizes[0] / 1024;                 // 65536
  const int blocks = (nrows + 3) / 4;                   // 4 waves (rows) per block
  hipLaunchKernelGGL(entmax_newton, dim3(blocks), dim3(256), 0, stream,
                     X, A, O, nrows);
}

// Round 3
// 127.636 us; speedup vs baseline: 8.7866x; 1.2583x over previous
//
#include <hip/hip_runtime.h>

// alpha-entmax: Newton on F(tau) = (sum (xs-tau)_+^p)^(1/p) - 1, p = 1/(alpha-1).
// F is a norm of an affine function of tau -> convex, decreasing, and
// asymptotically LINEAR for both sparse (p~1) and dense (p~100) heads, so
// Newton from tau0 = max-1 (F>=1 side) is monotone, overshoot-free, and
// converges in ~2-4 evaluations for every alpha regime.
// Last evaluation's p_j = u^(p-1)*u is kept in registers; sum(p) = f is already
// reduced, so the final pass is just normalize+store (no extra transcendentals).

__device__ __forceinline__ float wave_sum(float v) {
#pragma unroll
  for (int off = 32; off > 0; off >>= 1) v += __shfl_xor(v, off, 64);
  return v;
}
__device__ __forceinline__ float wave_max(float v) {
#pragma unroll
  for (int off = 32; off > 0; off >>= 1) v = fmaxf(v, __shfl_xor(v, off, 64));
  return v;
}

#define MAXIT 12

__global__ __launch_bounds__(256) void entmax_fnewton(
    const float* __restrict__ X, const float* __restrict__ A,
    float* __restrict__ O, int nrows) {
  const int lane = threadIdx.x & 63;
  const int wid  = threadIdx.x >> 6;
  const long long row = (long long)blockIdx.x * 4 + wid;
  if (row >= nrows) return;

  const float* xr = X + row * 1024;
  float* orow     = O + row * 1024;

  // rows are [B,H,Q] flattened; Q=1024 -> head = (row>>10) & 15
  const int h = (int)((row >> 10) & 15);
  const float a   = 1.01f + 0.98f * A[h];
  const float am1 = a - 1.0f;          // = 1/p
  const float inv = 1.0f / am1;        // = p, in (1.01, 100]
  const float c1  = inv - 1.0f;

  // load row, scale by (alpha-1)
  float xs[16];
#pragma unroll
  for (int c = 0; c < 4; ++c) {
    float4 t = reinterpret_cast<const float4*>(xr)[c * 64 + lane];
    xs[4*c+0] = t.x * am1; xs[4*c+1] = t.y * am1;
    xs[4*c+2] = t.z * am1; xs[4*c+3] = t.w * am1;
  }
  float m = xs[0];
#pragma unroll
  for (int j = 1; j < 16; ++j) m = fmaxf(m, xs[j]);
  m = wave_max(m);

  float tau = m - 1.0f;   // f(tau0) >= 1 (max element contributes exactly 1)
  float p[16];
  float f = 1.0f;

  for (int it = 0; it < MAXIT; ++it) {
    float fs = 0.0f, gs = 0.0f;
#pragma unroll
    for (int j = 0; j < 16; ++j) {
      float u  = fmaxf(xs[j] - tau, 0.0f);
      float l  = __builtin_amdgcn_logf(u);        // log2; log2(0) = -inf
      float e  = __builtin_amdgcn_exp2f(c1 * l);  // u^(p-1); exp2(-inf) = 0
      float pe = e * u;                           // u^p
      p[j] = pe;
      fs += pe;
      gs += e;
    }
    f = wave_sum(fs);
    const float g = wave_sum(gs);                 // wave-uniform
    if (!(g > 0.0f) || !(f > 0.0f)) break;
    // F = f^(1/p) = exp2(am1 * log2 f); Newton step on F - 1:
    // F' = -f^(1/p-1) * g  =>  step = (F-1)*f / (F*g)
    const float lf = __builtin_amdgcn_logf(f);
    const float F  = __builtin_amdgcn_exp2f(am1 * lf);
    float step = (F - 1.0f) * f / (F * g);
    step = fmaxf(step, 0.0f);                     // roundoff guard near F=1
    tau += step;
    if (!(step > 1e-7f * fmaxf(fabsf(tau), 1.0f))) break;  // wave-uniform
  }

  // p[] holds u^p at the converged tau; sum(p) = f. Normalize and store.
  const float r = 1.0f / f;
#pragma unroll
  for (int c = 0; c < 4; ++c) {
    float4 t;
    t.x = p[4*c+0] * r; t.y = p[4*c+1] * r;
    t.z = p[4*c+2] * r; t.w = p[4*c+3] * r;
    reinterpret_cast<float4*>(orow)[c * 64 + lane] = t;
  }
}

extern "C" void kernel_launch(void* const* d_in, const int* in_sizes, int n_in,
                              void* d_out, int out_size, void* d_ws, size_t ws_size,
                              hipStream_t stream) {
  const float* X = (const float*)d_in[0];
  const float* A = (const float*)d_in[1];
  float* O       = (float*)d_out;
  const int nrows = in_sizes[0] / 1024;                 // 65536
  const int blocks = (nrows + 3) / 4;                   // 4 rows (waves) per block
  hipLaunchKernelGGL(entmax_fnewton, dim3(blocks), dim3(256), 0, stream,
                     X, A, O, nrows);
}

// Round 4
// 120.884 us; speedup vs baseline: 9.2774x; 1.0559x over previous
//
#include <hip/hip_runtime.h>

// alpha-entmax, F-Newton (F = ||(xs-tau)_+||_p, p = 1/(alpha-1)) with
// active-set compaction:
//   tau is monotone nondecreasing from tau0 = max-1, so the active set
//   {j : xs[j] > tau0} is FIXED. Ballot-compact (value,index) into LDS,
//   pad to x64, and run Newton over K = ceil(n_act/64) elems/lane under a
//   wave-uniform branch -> sparse heads (alpha~2) do 1/16th the TRANS work.
// Final: zero LDS row, scatter normalized p by index, coalesced store.

__device__ __forceinline__ float wave_sum(float v) {
#pragma unroll
  for (int off = 32; off > 0; off >>= 1) v += __shfl_xor(v, off, 64);
  return v;
}
__device__ __forceinline__ float wave_max(float v) {
#pragma unroll
  for (int off = 32; off > 0; off >>= 1) v = fmaxf(v, __shfl_xor(v, off, 64));
  return v;
}

#define MAXIT 12

__global__ __launch_bounds__(256) void entmax_compact(
    const float* __restrict__ X, const float* __restrict__ A,
    float* __restrict__ O, int nrows) {
  __shared__ float          cval[4][1024];  // compacted values; reused as p-row
  __shared__ unsigned short cidx[4][1024];  // compacted row positions

  const int lane = threadIdx.x & 63;
  const int wid  = threadIdx.x >> 6;
  const long long row = (long long)blockIdx.x * 4 + wid;
  if (row >= nrows) return;

  const float* xr = X + row * 1024;
  float* orow     = O + row * 1024;

  const int h = (int)((row >> 10) & 15);     // [B,H,Q] flattened, Q=1024
  const float a   = 1.01f + 0.98f * A[h];
  const float am1 = a - 1.0f;                // = 1/p
  const float inv = 1.0f / am1;              // = p in (1.01, 100]
  const float c1  = inv - 1.0f;

  // load row, scale by (alpha-1); element 4c+k of lane l = row[c*256 + l*4 + k]
  float xs[16];
#pragma unroll
  for (int c = 0; c < 4; ++c) {
    float4 t = reinterpret_cast<const float4*>(xr)[c * 64 + lane];
    xs[4*c+0] = t.x * am1; xs[4*c+1] = t.y * am1;
    xs[4*c+2] = t.z * am1; xs[4*c+3] = t.w * am1;
  }
  float m = xs[0];
#pragma unroll
  for (int j = 1; j < 16; ++j) m = fmaxf(m, xs[j]);
  m = wave_max(m);
  const float tau0 = m - 1.0f;

  // ---- ballot-compact the fixed active set into LDS ----
  int base = 0;
#pragma unroll
  for (int c = 0; c < 4; ++c) {
#pragma unroll
    for (int k = 0; k < 4; ++k) {
      const int j = 4*c + k;
      const bool act = xs[j] > tau0;
      const unsigned long long mk = __ballot(act);
      if (act) {
        const int pos = base + __popcll(mk & ((1ull << lane) - 1ull));
        cval[wid][pos] = xs[j];
        cidx[wid][pos] = (unsigned short)(c * 256 + lane * 4 + k);
      }
      base += __popcll(mk);
    }
  }
  const int nact = __builtin_amdgcn_readfirstlane(base);   // >= 1 (the max)
  const int K    = (nact + 63) >> 6;                       // elems per lane
  for (int pos = nact + lane; pos < (K << 6); pos += 64)
    cval[wid][pos] = -3.0e38f;                             // pad: u == 0 forever
  asm volatile("s_waitcnt lgkmcnt(0)" ::: "memory");

  float vals[16];
#pragma unroll
  for (int k = 0; k < 16; ++k)
    if (k < K) vals[k] = cval[wid][lane + (k << 6)];

  // ---- F-Newton over the compacted set (identical math to full set) ----
  float tau = tau0;
  float p[16];
  float f = 1.0f;
  for (int it = 0; it < MAXIT; ++it) {
    float fs = 0.0f, gs = 0.0f;
#pragma unroll
    for (int k = 0; k < 16; ++k)
      if (k < K) {                                    // wave-uniform branch
        float u  = fmaxf(vals[k] - tau, 0.0f);
        float l  = __builtin_amdgcn_logf(u);          // log2(0) = -inf
        float e  = __builtin_amdgcn_exp2f(c1 * l);    // u^(p-1); exp2(-inf)=0
        float pe = e * u;                             // u^p
        p[k] = pe; fs += pe; gs += e;
      }
    f = wave_sum(fs);
    const float g = wave_sum(gs);
    if (!(g > 0.0f) || !(f > 0.0f)) break;
    const float lf = __builtin_amdgcn_logf(f);
    const float F  = __builtin_amdgcn_exp2f(am1 * lf); // f^(1/p)
    float step = (F - 1.0f) * f / (F * g);             // Newton on F-1
    step = fmaxf(step, 0.0f);                          // monotone; roundoff guard
    tau += step;
    if (!(step > 1e-7f * fmaxf(fabsf(tau), 1.0f))) break;
  }

  // ---- zero row in LDS, scatter normalized p, coalesced store ----
  const float r = 1.0f / f;
  const float4 z = make_float4(0.0f, 0.0f, 0.0f, 0.0f);
#pragma unroll
  for (int c = 0; c < 4; ++c)
    reinterpret_cast<float4*>(&cval[wid][0])[c * 64 + lane] = z;
  asm volatile("s_waitcnt lgkmcnt(0)" ::: "memory");
#pragma unroll
  for (int k = 0; k < 16; ++k)
    if (k < K) {
      const int pos = lane + (k << 6);
      if (pos < nact) cval[wid][cidx[wid][pos]] = p[k] * r;
    }
  asm volatile("s_waitcnt lgkmcnt(0)" ::: "memory");
#pragma unroll
  for (int c = 0; c < 4; ++c) {
    float4 t = reinterpret_cast<const float4*>(&cval[wid][0])[c * 64 + lane];
    reinterpret_cast<float4*>(orow)[c * 64 + lane] = t;
  }
}

extern "C" void kernel_launch(void* const* d_in, const int* in_sizes, int n_in,
                              void* d_out, int out_size, void* d_ws, size_t ws_size,
                              hipStream_t stream) {
  const float* X = (const float*)d_in[0];
  const float* A = (const float*)d_in[1];
  float* O       = (float*)d_out;
  const int nrows = in_sizes[0] / 1024;                 // 65536
  const int blocks = (nrows + 3) / 4;                   // 4 rows (waves) per block
  hipLaunchKernelGGL(entmax_compact, dim3(blocks), dim3(256), 0, stream,
                     X, A, O, nrows);
}